// Round 18
// baseline (268.572 us; speedup 1.0000x reference)
//
#include <hip/hip_runtime.h>
#include <math.h>

// CrossAttentionBlock: GN(32) -> q = xn@Wq^T ; k,v = text@W{k,v}^T ; cosine-sim
// attention (nh=8, hd=64, N_text=77) -> out@Wo^T + bo -> residual add.
// B=16, C=512, HW=4096, TD=768.  bf16 MFMA (16x16x32), fp32 accum.
// R18: R17 + attn2 widened to 512 q-rows/block (eight 64-row halves over one
//      K/V staging): grid 2048->1024; stage+transpose amortized 512x.

typedef unsigned short u16;
typedef __attribute__((ext_vector_type(8))) __bf16 bf16x8;
typedef __attribute__((ext_vector_type(4))) float f32x4;

typedef __attribute__((address_space(1))) unsigned int as1_u32;
typedef __attribute__((address_space(3))) unsigned int as3_u32;

__device__ __forceinline__ float b2f(u16 u) {
  union { unsigned int i; float f; } c; c.i = ((unsigned int)u) << 16; return c.f;
}
__device__ __forceinline__ u16 f2b(float f) {
  union { float f; unsigned int i; } c; c.f = f;
  unsigned int i = c.i + 0x7fffu + ((c.i >> 16) & 1u);  // RNE
  return (u16)(i >> 16);
}

// 16B-per-lane async global->LDS. LDS dest is wave-uniform base; HW adds lane*16.
__device__ __forceinline__ void g2lds16(const void* g, void* l) {
  __builtin_amdgcn_global_load_lds((const as1_u32*)g, (as3_u32*)l, 16, 0, 0);
}

// Merged prep: blocks 0..511 = GN stats (one block per (b,group));
// blocks 512..1023 = weight/text bf16 casts (grid-stride over 512 blocks).
__global__ __launch_bounds__(256) void k_prep(
    const float* __restrict__ x, float* __restrict__ stats,
    const float* __restrict__ Wq, const float* __restrict__ Wk,
    const float* __restrict__ Wv, const float* __restrict__ Wo,
    const float* __restrict__ text,
    u16* __restrict__ wq_b, u16* __restrict__ wkv_b,
    u16* __restrict__ wo_b, u16* __restrict__ text_b) {
  if (blockIdx.x >= 512) {
    const int i = (blockIdx.x - 512) * 256 + threadIdx.x;
    const int st = 512 * 256;
    for (int j = i; j < 262144; j += st) wq_b[j] = f2b(Wq[j]);
    for (int j = i; j < 393216; j += st) wkv_b[j] = f2b(Wk[j]);
    for (int j = i; j < 393216; j += st) wkv_b[393216 + j] = f2b(Wv[j]);
    for (int j = i; j < 262144; j += st) wo_b[j] = f2b(Wo[j]);
    for (int j = i; j < 946176; j += st) text_b[j] = f2b(text[j]);
    return;
  }
  const int bg = blockIdx.x;
  const float4* p = (const float4*)(x + (size_t)bg * 65536);
  float s = 0.f, ss = 0.f;
  for (int i = threadIdx.x; i < 16384; i += 256) {
    float4 v = p[i];
    s  += v.x + v.y + v.z + v.w;
    ss += v.x*v.x + v.y*v.y + v.z*v.z + v.w*v.w;
  }
  for (int o = 1; o < 64; o <<= 1) { s += __shfl_xor(s, o, 64); ss += __shfl_xor(ss, o, 64); }
  __shared__ float as_[4], bs_[4];
  int w = threadIdx.x >> 6;
  if ((threadIdx.x & 63) == 0) { as_[w] = s; bs_[w] = ss; }
  __syncthreads();
  if (threadIdx.x == 0) {
    s  = as_[0] + as_[1] + as_[2] + as_[3];
    ss = bs_[0] + bs_[1] + bs_[2] + bs_[3];
    float mu  = s * (1.f / 65536.f);
    float var = ss * (1.f / 65536.f) - mu * mu;
    stats[2*bg]   = mu;
    stats[2*bg+1] = rsqrtf(var + 1e-5f);
  }
}

// Combined launch:
//  blocks 0..1023   : fused GN + Q-projection + per-head q L2-norm (R9 path).
//  blocks 1024..1103: KV GEMM with fused per-head k L2-norm epilogue.
__global__ __launch_bounds__(256, 2) void k_qproj_kv(
    const float* __restrict__ x, const float* __restrict__ stats,
    const float* __restrict__ gw, const float* __restrict__ gb,
    const u16* __restrict__ Wqb, u16* __restrict__ qb,
    const u16* __restrict__ textb, const u16* __restrict__ wkvb,
    u16* __restrict__ kn, u16* __restrict__ vn) {
  __shared__ u16 Al[128 * 64];
  __shared__ u16 Bl[256 * 64];
  __shared__ float cw[512], cb[512];
  const int tid = threadIdx.x;
  const int l = tid & 63, w = tid >> 6;
  const int lr = l & 15, lg = l >> 4;
  const int lg4 = lg << 2;
  const int rl = l >> 3, slot = l & 7;
  const int c8 = (slot ^ rl) << 3;

  if (blockIdx.x >= 1024) {
    // ---------------- KV GEMM path ----------------
    const int kb = blockIdx.x - 1024;
    const int m0 = (kb >> 3) << 7, n0 = (kb & 7) << 7;
    const int wm = (w >> 1) << 6, wn = (w & 1) << 6;

    f32x4 acc[4][4];
#pragma unroll
    for (int i = 0; i < 4; ++i)
#pragma unroll
      for (int j = 0; j < 4; ++j) acc[i][j] = {0.f, 0.f, 0.f, 0.f};

    int arow[4], brow[4];
#pragma unroll
    for (int j = 0; j < 4; ++j) {
      const int r_local = (w << 5) + (j << 3) + rl;
      arow[j] = min(m0 + r_local, 1231);
      brow[j] = n0 + r_local;
    }

    for (int ks = 0; ks < 12; ++ks) {
      const int kcol = (ks << 6) + c8;
#pragma unroll
      for (int j = 0; j < 4; ++j)
        g2lds16(textb + (size_t)arow[j] * 768 + kcol, Al + (((w << 5) + (j << 3)) << 6));
#pragma unroll
      for (int j = 0; j < 4; ++j)
        g2lds16(wkvb + (size_t)brow[j] * 768 + kcol, Bl + (((w << 5) + (j << 3)) << 6));
      __syncthreads();
      bf16x8 bfr[4][2];
#pragma unroll
      for (int j = 0; j < 4; ++j) {
        const int br = wn + j * 16 + lr;
        bfr[j][0] = *(const bf16x8*)(Bl + (br << 6) + (((lg    ) ^ (br & 7)) << 3));
        bfr[j][1] = *(const bf16x8*)(Bl + (br << 6) + (((lg + 4) ^ (br & 7)) << 3));
      }
#pragma unroll
      for (int i = 0; i < 4; ++i) {
        const int ar = wm + i * 16 + lr;
        const bf16x8 a0 = *(const bf16x8*)(Al + (ar << 6) + (((lg    ) ^ (ar & 7)) << 3));
        const bf16x8 a1 = *(const bf16x8*)(Al + (ar << 6) + (((lg + 4) ^ (ar & 7)) << 3));
#pragma unroll
        for (int j = 0; j < 4; ++j) {
          acc[i][j] = __builtin_amdgcn_mfma_f32_16x16x32_bf16(a0, bfr[j][0], acc[i][j], 0, 0, 0);
          acc[i][j] = __builtin_amdgcn_mfma_f32_16x16x32_bf16(a1, bfr[j][1], acc[i][j], 0, 0, 0);
        }
      }
      __syncthreads();
    }

    // fused epilogue: cols 0-511 = k (per-head L2 norm), 512-1023 = v (cast).
    const int col0 = n0 + wn;
#pragma unroll
    for (int i = 0; i < 4; ++i) {
#pragma unroll
      for (int r = 0; r < 4; ++r) {
        const int row = m0 + wm + i * 16 + lg4 + r;
        if (row < 1232) {
          const int bq = row / 77, tq = row - bq * 77;
          if (col0 < 512) {
            float ss = 0.f;
#pragma unroll
            for (int j = 0; j < 4; ++j) { const float v = acc[i][j][r]; ss += v * v; }
            ss += __shfl_xor(ss, 1, 64); ss += __shfl_xor(ss, 2, 64);
            ss += __shfl_xor(ss, 4, 64); ss += __shfl_xor(ss, 8, 64);
            const float sc = 1.f / (sqrtf(ss) + 1e-6f);
            const int h = col0 >> 6;
            const size_t ob = (((size_t)(bq * 8 + h)) * 77 + tq) * 64;
#pragma unroll
            for (int j = 0; j < 4; ++j)
              kn[ob + j * 16 + lr] = f2b(acc[i][j][r] * sc);
          } else {
            const int h = (col0 - 512) >> 6;
            const size_t ob = (((size_t)(bq * 8 + h)) * 77 + tq) * 64;
#pragma unroll
            for (int j = 0; j < 4; ++j)
              vn[ob + j * 16 + lr] = f2b(acc[i][j][r]);
          }
        }
      }
    }
    return;
  }

  // ---------------- qproj path (R9, unchanged) ----------------
  const int o = blockIdx.x;
  const int mi = ((o >> 4) << 3) + (o & 7);   // 0..511 token tile
  const int ni = (o >> 3) & 1;                // 0..1   out-channel half
  const int m0 = mi << 7, n0 = ni << 8;
  const int b = m0 >> 12, hw0 = m0 & 4095;

  for (int c = tid; c < 512; c += 256) {
    const int g = (b << 5) + (c >> 4);
    const float mu = stats[2*g], rs = stats[2*g+1];
    const float wg = gw[c] * rs;
    cw[c] = wg; cb[c] = gb[c] - mu * wg;
  }

  const int wm = (w & 1) << 6;          // token base within tile
  const int wn = (w >> 1) << 7;         // out-ch base within tile

  f32x4 acc[4][8];
#pragma unroll
  for (int i = 0; i < 4; ++i)
#pragma unroll
    for (int j = 0; j < 8; ++j) acc[i][j] = {0.f, 0.f, 0.f, 0.f};

  int brow[8];
#pragma unroll
  for (int j = 0; j < 8; ++j) brow[j] = n0 + (w << 6) + (j << 3) + rl;

  const int tokl = tid & 127;
  const int chg = tid >> 7;
  const float* xb = x + (((size_t)b) << 9) * 4096;
  __syncthreads();  // cw/cb ready

  for (int ks = 0; ks < 8; ++ks) {
#pragma unroll
    for (int j = 0; j < 8; ++j)
      g2lds16(Wqb + (size_t)brow[j] * 512 + (ks << 6) + c8,
              Bl + (((w << 6) + (j << 3)) << 6));
    // A tile: 8 iters x 4 channels, 1 token per thread
#pragma unroll
    for (int jj = 0; jj < 8; ++jj) {
      const int ch4 = (((chg << 3) + jj) << 2);   // 0..60 step 4
      const int c = (ks << 6) + ch4;
      const float v0 = xb[(size_t)(c + 0) * 4096 + hw0 + tokl];
      const float v1 = xb[(size_t)(c + 1) * 4096 + hw0 + tokl];
      const float v2 = xb[(size_t)(c + 2) * 4096 + hw0 + tokl];
      const float v3 = xb[(size_t)(c + 3) * 4096 + hw0 + tokl];
      union { __bf16 h[4]; ushort4 u; } pk;
      pk.h[0] = (__bf16)(v0 * cw[c + 0] + cb[c + 0]);
      pk.h[1] = (__bf16)(v1 * cw[c + 1] + cb[c + 1]);
      pk.h[2] = (__bf16)(v2 * cw[c + 2] + cb[c + 2]);
      pk.h[3] = (__bf16)(v3 * cw[c + 3] + cb[c + 3]);
      const int sl = (((ch4 >> 3) ^ (tokl & 7)) << 3) + (ch4 & 7);
      *(ushort4*)(Al + (tokl << 6) + sl) = pk.u;
    }
    __syncthreads();
    bf16x8 af[4][2];
#pragma unroll
    for (int i = 0; i < 4; ++i) {
      const int ar = wm + i * 16 + lr;
      af[i][0] = *(const bf16x8*)(Al + (ar << 6) + (((lg    ) ^ (ar & 7)) << 3));
      af[i][1] = *(const bf16x8*)(Al + (ar << 6) + (((lg + 4) ^ (ar & 7)) << 3));
    }
#pragma unroll
    for (int j = 0; j < 8; ++j) {
      const int br = wn + j * 16 + lr;
      const bf16x8 b0 = *(const bf16x8*)(Bl + (br << 6) + (((lg    ) ^ (br & 7)) << 3));
      const bf16x8 b1 = *(const bf16x8*)(Bl + (br << 6) + (((lg + 4) ^ (br & 7)) << 3));
#pragma unroll
      for (int i = 0; i < 4; ++i) {
        acc[i][j] = __builtin_amdgcn_mfma_f32_16x16x32_bf16(af[i][0], b0, acc[i][j], 0, 0, 0);
        acc[i][j] = __builtin_amdgcn_mfma_f32_16x16x32_bf16(af[i][1], b1, acc[i][j], 0, 0, 0);
      }
    }
    __syncthreads();
  }

  // epilogue: per-head (64-col group = 4 j-frags) L2 normalization, bf16 out
#pragma unroll
  for (int i = 0; i < 4; ++i) {
#pragma unroll
    for (int r = 0; r < 4; ++r) {
      const int row = m0 + wm + i * 16 + lg4 + r;
#pragma unroll
      for (int h2 = 0; h2 < 2; ++h2) {
        float ss = 0.f;
#pragma unroll
        for (int j = h2 * 4; j < h2 * 4 + 4; ++j) {
          const float v = acc[i][j][r]; ss += v * v;
        }
        ss += __shfl_xor(ss, 1, 64); ss += __shfl_xor(ss, 2, 64);
        ss += __shfl_xor(ss, 4, 64); ss += __shfl_xor(ss, 8, 64);
        const float sc = 1.f / (sqrtf(ss) + 1e-6f);
#pragma unroll
        for (int j = h2 * 4; j < h2 * 4 + 4; ++j)
          qb[(size_t)row * 512 + n0 + wn + j * 16 + lr] = f2b(acc[i][j][r] * sc);
      }
    }
  }
}

// O-proj GEMM (proven R9 structure, unchanged).
__global__ __launch_bounds__(256) void k_gemm2(
    const u16* __restrict__ A, const u16* __restrict__ BT,
    int M, int N, int K,
    float* __restrict__ outf,
    const float* __restrict__ xres, const float* __restrict__ bias) {
  __shared__ u16 Al[128 * 64];
  __shared__ u16 Bl[128 * 64];
  const int tid = threadIdx.x;
  const int l = tid & 63, w = tid >> 6;

  const int nwg = gridDim.x * gridDim.y;
  int lin = blockIdx.y * gridDim.x + blockIdx.x;
  lin = (lin & 7) * (nwg >> 3) + (lin >> 3);
  const int m0 = (lin / gridDim.x) << 7, n0 = (lin % gridDim.x) << 7;

  const int wm = (w >> 1) << 6, wn = (w & 1) << 6;
  const int lr = l & 15, lg = l >> 4;

  f32x4 acc[4][4];
#pragma unroll
  for (int i = 0; i < 4; ++i)
#pragma unroll
    for (int j = 0; j < 4; ++j) acc[i][j] = {0.f, 0.f, 0.f, 0.f};

  const int rl = l >> 3, slot = l & 7;
  const int c8 = (slot ^ rl) << 3;
  int arow[4], brow[4];
#pragma unroll
  for (int j = 0; j < 4; ++j) {
    const int r_local = (w << 5) + (j << 3) + rl;
    arow[j] = min(m0 + r_local, M - 1);
    brow[j] = n0 + r_local;
  }

  const int ksteps = K >> 6;
  for (int ks = 0; ks < ksteps; ++ks) {
    const int kb = (ks << 6) + c8;
#pragma unroll
    for (int j = 0; j < 4; ++j)
      g2lds16(A + (size_t)arow[j] * K + kb, Al + (((w << 5) + (j << 3)) << 6));
#pragma unroll
    for (int j = 0; j < 4; ++j)
      g2lds16(BT + (size_t)brow[j] * K + kb, Bl + (((w << 5) + (j << 3)) << 6));
    __syncthreads();
    bf16x8 bfr[4][2];
#pragma unroll
    for (int j = 0; j < 4; ++j) {
      const int br = wn + j * 16 + lr;
      bfr[j][0] = *(const bf16x8*)(Bl + (br << 6) + (((lg    ) ^ (br & 7)) << 3));
      bfr[j][1] = *(const bf16x8*)(Bl + (br << 6) + (((lg + 4) ^ (br & 7)) << 3));
    }
#pragma unroll
    for (int i = 0; i < 4; ++i) {
      const int ar = wm + i * 16 + lr;
      const bf16x8 a0 = *(const bf16x8*)(Al + (ar << 6) + (((lg    ) ^ (ar & 7)) << 3));
      const bf16x8 a1 = *(const bf16x8*)(Al + (ar << 6) + (((lg + 4) ^ (ar & 7)) << 3));
#pragma unroll
      for (int j = 0; j < 4; ++j) {
        acc[i][j] = __builtin_amdgcn_mfma_f32_16x16x32_bf16(a0, bfr[j][0], acc[i][j], 0, 0, 0);
        acc[i][j] = __builtin_amdgcn_mfma_f32_16x16x32_bf16(a1, bfr[j][1], acc[i][j], 0, 0, 0);
      }
    }
    __syncthreads();
  }

  const int lg4 = lg << 2;
#pragma unroll
  for (int i = 0; i < 4; ++i) {
#pragma unroll
    for (int j = 0; j < 4; ++j) {
#pragma unroll
      for (int r = 0; r < 4; ++r) {
        const int row = m0 + wm + i * 16 + lg4 + r;
        const int col = n0 + wn + j * 16 + lr;
        const int bb = col >> 12, hw = col & 4095;
        const size_t oo = (((size_t)bb << 9) + row) * 4096 + hw;
        outf[oo] = xres[oo] + bias[row] + acc[i][j][r];
      }
    }
  }
}

// MFMA attention. R18: 512 q-rows per block as eight 64-row halves over a
// single K/V staging (grid 1024; stage+transpose amortized 512x).
__global__ __launch_bounds__(256) void k_attn2(
    const u16* __restrict__ q, const u16* __restrict__ kn,
    const u16* __restrict__ vn, u16* __restrict__ out) {
  __shared__ u16 Kl[96 * 72];
  __shared__ u16 Vt[64 * 104];
  __shared__ u16 Pl[64 * 104];
  const int qt = blockIdx.x, h = blockIdx.y, b = blockIdx.z;
  const size_t kvb = ((size_t)(b * 8 + h)) * (77 * 64);
  const int tid = threadIdx.x;
  for (int u = tid; u < 768; u += 256) {
    const int row = u >> 3, c8v = (u & 7) << 3;
    uint4 v = make_uint4(0, 0, 0, 0);
    if (row < 77) v = *(const uint4*)(kn + kvb + row * 64 + c8v);
    *(uint4*)(Kl + row * 72 + c8v) = v;
  }
  for (int u = tid; u < 768; u += 256) {
    const int row = u >> 3, c8v = (u & 7) << 3;
    uint4 v = make_uint4(0, 0, 0, 0);
    if (row < 77) v = *(const uint4*)(vn + kvb + row * 64 + c8v);
    const u16* pv = (const u16*)&v;
#pragma unroll
    for (int j = 0; j < 8; ++j) Vt[(c8v + j) * 104 + row] = pv[j];
  }
  __syncthreads();
  const int l = tid & 63, w = tid >> 6;
  const int lr = l & 15, lg = l >> 4;

  for (int half = 0; half < 8; ++half) {
    const int qrow = (b << 12) + (qt << 9) + (half << 6) + (w << 4) + lr;
    bf16x8 af0 = *(const bf16x8*)(q + (size_t)qrow * 512 + h * 64 + lg * 8);
    bf16x8 af1 = *(const bf16x8*)(q + (size_t)qrow * 512 + h * 64 + 32 + lg * 8);
    f32x4 s[6];
#pragma unroll
    for (int nt = 0; nt < 6; ++nt) {
      s[nt] = {0.f, 0.f, 0.f, 0.f};
      bf16x8 bk0 = *(const bf16x8*)(Kl + (nt * 16 + lr) * 72 + lg * 8);
      bf16x8 bk1 = *(const bf16x8*)(Kl + (nt * 16 + lr) * 72 + 32 + lg * 8);
      s[nt] = __builtin_amdgcn_mfma_f32_16x16x32_bf16(af0, bk0, s[nt], 0, 0, 0);
      s[nt] = __builtin_amdgcn_mfma_f32_16x16x32_bf16(af1, bk1, s[nt], 0, 0, 0);
    }
#pragma unroll
    for (int r = 0; r < 4; ++r) {
      if (lr >= 13) s[4][r] = -1e30f;
      s[5][r] = -1e30f;
    }
#pragma unroll
    for (int r = 0; r < 4; ++r) {
      float m = s[0][r];
#pragma unroll
      for (int nt = 1; nt < 6; ++nt) m = fmaxf(m, s[nt][r]);
      m = fmaxf(m, __shfl_xor(m, 1, 64)); m = fmaxf(m, __shfl_xor(m, 2, 64));
      m = fmaxf(m, __shfl_xor(m, 4, 64)); m = fmaxf(m, __shfl_xor(m, 8, 64));
      float sum = 0.f;
#pragma unroll
      for (int nt = 0; nt < 6; ++nt) { s[nt][r] = __expf(s[nt][r] - m); sum += s[nt][r]; }
      sum += __shfl_xor(sum, 1, 64); sum += __shfl_xor(sum, 2, 64);
      sum += __shfl_xor(sum, 4, 64); sum += __shfl_xor(sum, 8, 64);
      const float inv = 1.f / sum;
      const int qlocal = (w << 4) + (lg << 2) + r;
#pragma unroll
      for (int nt = 0; nt < 6; ++nt)
        Pl[qlocal * 104 + nt * 16 + lr] = f2b(s[nt][r] * inv);
    }
    __syncthreads();

    bf16x8 pa0 = *(const bf16x8*)(Pl + ((w << 4) + lr) * 104 + lg * 8);
    bf16x8 pa1 = *(const bf16x8*)(Pl + ((w << 4) + lr) * 104 + 32 + lg * 8);
    bf16x8 pa2 = *(const bf16x8*)(Pl + ((w << 4) + lr) * 104 + 64 + lg * 8);
    f32x4 o[4];
#pragma unroll
    for (int nt = 0; nt < 4; ++nt) {
      o[nt] = {0.f, 0.f, 0.f, 0.f};
      bf16x8 bv0 = *(const bf16x8*)(Vt + (nt * 16 + lr) * 104 + lg * 8);
      bf16x8 bv1 = *(const bf16x8*)(Vt + (nt * 16 + lr) * 104 + 32 + lg * 8);
      bf16x8 bv2 = *(const bf16x8*)(Vt + (nt * 16 + lr) * 104 + 64 + lg * 8);
      o[nt] = __builtin_amdgcn_mfma_f32_16x16x32_bf16(pa0, bv0, o[nt], 0, 0, 0);
      o[nt] = __builtin_amdgcn_mfma_f32_16x16x32_bf16(pa1, bv1, o[nt], 0, 0, 0);
      o[nt] = __builtin_amdgcn_mfma_f32_16x16x32_bf16(pa2, bv2, o[nt], 0, 0, 0);
    }
#pragma unroll
    for (int r = 0; r < 4; ++r) {
      const int n = (b << 12) + (qt << 9) + (half << 6) + (w << 4) + (lg << 2) + r;
#pragma unroll
      for (int nt = 0; nt < 4; ++nt)
        out[(size_t)n * 512 + h * 64 + nt * 16 + lr] = f2b(o[nt][r]);
    }
    __syncthreads();   // all waves done reading Pl before next half rewrites
  }
}

extern "C" void kernel_launch(void* const* d_in, const int* in_sizes, int n_in,
                              void* d_out, int out_size, void* d_ws, size_t ws_size,
                              hipStream_t stream) {
  (void)in_sizes; (void)n_in; (void)out_size; (void)ws_size;
  const float* x    = (const float*)d_in[0];
  const float* text = (const float*)d_in[1];
  const float* gnw  = (const float*)d_in[2];
  const float* gnb  = (const float*)d_in[3];
  const float* Wq   = (const float*)d_in[4];
  const float* Wk   = (const float*)d_in[5];
  const float* Wv   = (const float*)d_in[6];
  const float* Wo   = (const float*)d_in[7];
  const float* bo   = (const float*)d_in[8];
  float* out = (float*)d_out;

  char* ws = (char*)d_ws;
  size_t off = 0;
  auto alloc = [&](size_t bytes) -> void* {
    void* p = ws + off; off += (bytes + 255) & ~(size_t)255; return p;
  };
  float* stats = (float*)alloc(512 * 2 * 4);
  u16* wq_b    = (u16*)alloc((size_t)512 * 512 * 2);
  u16* wkv_b   = (u16*)alloc((size_t)1024 * 768 * 2);
  u16* wo_b    = (u16*)alloc((size_t)512 * 512 * 2);
  u16* text_b  = (u16*)alloc((size_t)1232 * 768 * 2);
  u16* kn      = (u16*)alloc((size_t)16 * 8 * 77 * 64 * 2);
  u16* vn      = (u16*)alloc((size_t)16 * 8 * 77 * 64 * 2);
  u16* ao      = (u16*)alloc((size_t)65536 * 512 * 2);  // attention output
  u16* qb      = (u16*)alloc((size_t)65536 * 512 * 2);

  // blocks 0..511: GN stats; blocks 512..1023: weight/text bf16 casts
  k_prep<<<dim3(1024), 256, 0, stream>>>(x, stats, Wq, Wk, Wv, Wo, text,
                                         wq_b, wkv_b, wo_b, text_b);

  // blocks 0..1023: q = gn(x)^T @ Wq^T (fused GN + q-norm)
  // blocks 1024..1103: kn/vn = text @ Wkv^T with fused per-head k-norm
  k_qproj_kv<<<dim3(1104), 256, 0, stream>>>(x, stats, gnw, gnb, wq_b, qb,
                                             text_b, wkv_b, kn, vn);

  k_attn2<<<dim3(8, 8, 16), 256, 0, stream>>>(qb, kn, vn, ao);

  // out^T = Wo @ attn^T with fused bias + residual, written as [B,C,HW]
  k_gemm2<<<dim3(512, 4), 256, 0, stream>>>(wo_b, ao, 512, 65536, 512,
                                            out, x, bo);
}

// Round 19
// 268.276 us; speedup vs baseline: 1.0011x; 1.0011x over previous
//
#include <hip/hip_runtime.h>
#include <math.h>

// CrossAttentionBlock: GN(32) -> q = xn@Wq^T ; k,v = text@W{k,v}^T ; cosine-sim
// attention (nh=8, hd=64, N_text=77) -> out@Wo^T + bo -> residual add.
// B=16, C=512, HW=4096, TD=768.  bf16 MFMA (16x16x32), fp32 accum.
// R19: exact R17 restore (best measured, 267.9us). R18's 512-row attn2 was
//      within-noise-negative -> amortization ladder exhausted at 256 rows.
//      Terminal config: k_prep (gnstats+casts packed) -> k_qproj_kv (GN+Qproj
//      +qnorm || KV GEMM+knorm) -> k_attn2 (256 rows/block, 4 halves/stage)
//      -> k_gemm2 (O-proj + bias + residual fused epilogue).

typedef unsigned short u16;
typedef __attribute__((ext_vector_type(8))) __bf16 bf16x8;
typedef __attribute__((ext_vector_type(4))) float f32x4;

typedef __attribute__((address_space(1))) unsigned int as1_u32;
typedef __attribute__((address_space(3))) unsigned int as3_u32;

__device__ __forceinline__ float b2f(u16 u) {
  union { unsigned int i; float f; } c; c.i = ((unsigned int)u) << 16; return c.f;
}
__device__ __forceinline__ u16 f2b(float f) {
  union { float f; unsigned int i; } c; c.f = f;
  unsigned int i = c.i + 0x7fffu + ((c.i >> 16) & 1u);  // RNE
  return (u16)(i >> 16);
}

// 16B-per-lane async global->LDS. LDS dest is wave-uniform base; HW adds lane*16.
__device__ __forceinline__ void g2lds16(const void* g, void* l) {
  __builtin_amdgcn_global_load_lds((const as1_u32*)g, (as3_u32*)l, 16, 0, 0);
}

// Merged prep: blocks 0..511 = GN stats (one block per (b,group));
// blocks 512..1023 = weight/text bf16 casts (grid-stride over 512 blocks).
__global__ __launch_bounds__(256) void k_prep(
    const float* __restrict__ x, float* __restrict__ stats,
    const float* __restrict__ Wq, const float* __restrict__ Wk,
    const float* __restrict__ Wv, const float* __restrict__ Wo,
    const float* __restrict__ text,
    u16* __restrict__ wq_b, u16* __restrict__ wkv_b,
    u16* __restrict__ wo_b, u16* __restrict__ text_b) {
  if (blockIdx.x >= 512) {
    const int i = (blockIdx.x - 512) * 256 + threadIdx.x;
    const int st = 512 * 256;
    for (int j = i; j < 262144; j += st) wq_b[j] = f2b(Wq[j]);
    for (int j = i; j < 393216; j += st) wkv_b[j] = f2b(Wk[j]);
    for (int j = i; j < 393216; j += st) wkv_b[393216 + j] = f2b(Wv[j]);
    for (int j = i; j < 262144; j += st) wo_b[j] = f2b(Wo[j]);
    for (int j = i; j < 946176; j += st) text_b[j] = f2b(text[j]);
    return;
  }
  const int bg = blockIdx.x;
  const float4* p = (const float4*)(x + (size_t)bg * 65536);
  float s = 0.f, ss = 0.f;
  for (int i = threadIdx.x; i < 16384; i += 256) {
    float4 v = p[i];
    s  += v.x + v.y + v.z + v.w;
    ss += v.x*v.x + v.y*v.y + v.z*v.z + v.w*v.w;
  }
  for (int o = 1; o < 64; o <<= 1) { s += __shfl_xor(s, o, 64); ss += __shfl_xor(ss, o, 64); }
  __shared__ float as_[4], bs_[4];
  int w = threadIdx.x >> 6;
  if ((threadIdx.x & 63) == 0) { as_[w] = s; bs_[w] = ss; }
  __syncthreads();
  if (threadIdx.x == 0) {
    s  = as_[0] + as_[1] + as_[2] + as_[3];
    ss = bs_[0] + bs_[1] + bs_[2] + bs_[3];
    float mu  = s * (1.f / 65536.f);
    float var = ss * (1.f / 65536.f) - mu * mu;
    stats[2*bg]   = mu;
    stats[2*bg+1] = rsqrtf(var + 1e-5f);
  }
}

// Combined launch:
//  blocks 0..1023   : fused GN + Q-projection + per-head q L2-norm (R9 path).
//  blocks 1024..1103: KV GEMM with fused per-head k L2-norm epilogue.
__global__ __launch_bounds__(256, 2) void k_qproj_kv(
    const float* __restrict__ x, const float* __restrict__ stats,
    const float* __restrict__ gw, const float* __restrict__ gb,
    const u16* __restrict__ Wqb, u16* __restrict__ qb,
    const u16* __restrict__ textb, const u16* __restrict__ wkvb,
    u16* __restrict__ kn, u16* __restrict__ vn) {
  __shared__ u16 Al[128 * 64];
  __shared__ u16 Bl[256 * 64];
  __shared__ float cw[512], cb[512];
  const int tid = threadIdx.x;
  const int l = tid & 63, w = tid >> 6;
  const int lr = l & 15, lg = l >> 4;
  const int lg4 = lg << 2;
  const int rl = l >> 3, slot = l & 7;
  const int c8 = (slot ^ rl) << 3;

  if (blockIdx.x >= 1024) {
    // ---------------- KV GEMM path ----------------
    const int kb = blockIdx.x - 1024;
    const int m0 = (kb >> 3) << 7, n0 = (kb & 7) << 7;
    const int wm = (w >> 1) << 6, wn = (w & 1) << 6;

    f32x4 acc[4][4];
#pragma unroll
    for (int i = 0; i < 4; ++i)
#pragma unroll
      for (int j = 0; j < 4; ++j) acc[i][j] = {0.f, 0.f, 0.f, 0.f};

    int arow[4], brow[4];
#pragma unroll
    for (int j = 0; j < 4; ++j) {
      const int r_local = (w << 5) + (j << 3) + rl;
      arow[j] = min(m0 + r_local, 1231);
      brow[j] = n0 + r_local;
    }

    for (int ks = 0; ks < 12; ++ks) {
      const int kcol = (ks << 6) + c8;
#pragma unroll
      for (int j = 0; j < 4; ++j)
        g2lds16(textb + (size_t)arow[j] * 768 + kcol, Al + (((w << 5) + (j << 3)) << 6));
#pragma unroll
      for (int j = 0; j < 4; ++j)
        g2lds16(wkvb + (size_t)brow[j] * 768 + kcol, Bl + (((w << 5) + (j << 3)) << 6));
      __syncthreads();
      bf16x8 bfr[4][2];
#pragma unroll
      for (int j = 0; j < 4; ++j) {
        const int br = wn + j * 16 + lr;
        bfr[j][0] = *(const bf16x8*)(Bl + (br << 6) + (((lg    ) ^ (br & 7)) << 3));
        bfr[j][1] = *(const bf16x8*)(Bl + (br << 6) + (((lg + 4) ^ (br & 7)) << 3));
      }
#pragma unroll
      for (int i = 0; i < 4; ++i) {
        const int ar = wm + i * 16 + lr;
        const bf16x8 a0 = *(const bf16x8*)(Al + (ar << 6) + (((lg    ) ^ (ar & 7)) << 3));
        const bf16x8 a1 = *(const bf16x8*)(Al + (ar << 6) + (((lg + 4) ^ (ar & 7)) << 3));
#pragma unroll
        for (int j = 0; j < 4; ++j) {
          acc[i][j] = __builtin_amdgcn_mfma_f32_16x16x32_bf16(a0, bfr[j][0], acc[i][j], 0, 0, 0);
          acc[i][j] = __builtin_amdgcn_mfma_f32_16x16x32_bf16(a1, bfr[j][1], acc[i][j], 0, 0, 0);
        }
      }
      __syncthreads();
    }

    // fused epilogue: cols 0-511 = k (per-head L2 norm), 512-1023 = v (cast).
    const int col0 = n0 + wn;
#pragma unroll
    for (int i = 0; i < 4; ++i) {
#pragma unroll
      for (int r = 0; r < 4; ++r) {
        const int row = m0 + wm + i * 16 + lg4 + r;
        if (row < 1232) {
          const int bq = row / 77, tq = row - bq * 77;
          if (col0 < 512) {
            float ss = 0.f;
#pragma unroll
            for (int j = 0; j < 4; ++j) { const float v = acc[i][j][r]; ss += v * v; }
            ss += __shfl_xor(ss, 1, 64); ss += __shfl_xor(ss, 2, 64);
            ss += __shfl_xor(ss, 4, 64); ss += __shfl_xor(ss, 8, 64);
            const float sc = 1.f / (sqrtf(ss) + 1e-6f);
            const int h = col0 >> 6;
            const size_t ob = (((size_t)(bq * 8 + h)) * 77 + tq) * 64;
#pragma unroll
            for (int j = 0; j < 4; ++j)
              kn[ob + j * 16 + lr] = f2b(acc[i][j][r] * sc);
          } else {
            const int h = (col0 - 512) >> 6;
            const size_t ob = (((size_t)(bq * 8 + h)) * 77 + tq) * 64;
#pragma unroll
            for (int j = 0; j < 4; ++j)
              vn[ob + j * 16 + lr] = f2b(acc[i][j][r]);
          }
        }
      }
    }
    return;
  }

  // ---------------- qproj path (R9, unchanged) ----------------
  const int o = blockIdx.x;
  const int mi = ((o >> 4) << 3) + (o & 7);   // 0..511 token tile
  const int ni = (o >> 3) & 1;                // 0..1   out-channel half
  const int m0 = mi << 7, n0 = ni << 8;
  const int b = m0 >> 12, hw0 = m0 & 4095;

  for (int c = tid; c < 512; c += 256) {
    const int g = (b << 5) + (c >> 4);
    const float mu = stats[2*g], rs = stats[2*g+1];
    const float wg = gw[c] * rs;
    cw[c] = wg; cb[c] = gb[c] - mu * wg;
  }

  const int wm = (w & 1) << 6;          // token base within tile
  const int wn = (w >> 1) << 7;         // out-ch base within tile

  f32x4 acc[4][8];
#pragma unroll
  for (int i = 0; i < 4; ++i)
#pragma unroll
    for (int j = 0; j < 8; ++j) acc[i][j] = {0.f, 0.f, 0.f, 0.f};

  int brow[8];
#pragma unroll
  for (int j = 0; j < 8; ++j) brow[j] = n0 + (w << 6) + (j << 3) + rl;

  const int tokl = tid & 127;
  const int chg = tid >> 7;
  const float* xb = x + (((size_t)b) << 9) * 4096;
  __syncthreads();  // cw/cb ready

  for (int ks = 0; ks < 8; ++ks) {
#pragma unroll
    for (int j = 0; j < 8; ++j)
      g2lds16(Wqb + (size_t)brow[j] * 512 + (ks << 6) + c8,
              Bl + (((w << 6) + (j << 3)) << 6));
    // A tile: 8 iters x 4 channels, 1 token per thread
#pragma unroll
    for (int jj = 0; jj < 8; ++jj) {
      const int ch4 = (((chg << 3) + jj) << 2);   // 0..60 step 4
      const int c = (ks << 6) + ch4;
      const float v0 = xb[(size_t)(c + 0) * 4096 + hw0 + tokl];
      const float v1 = xb[(size_t)(c + 1) * 4096 + hw0 + tokl];
      const float v2 = xb[(size_t)(c + 2) * 4096 + hw0 + tokl];
      const float v3 = xb[(size_t)(c + 3) * 4096 + hw0 + tokl];
      union { __bf16 h[4]; ushort4 u; } pk;
      pk.h[0] = (__bf16)(v0 * cw[c + 0] + cb[c + 0]);
      pk.h[1] = (__bf16)(v1 * cw[c + 1] + cb[c + 1]);
      pk.h[2] = (__bf16)(v2 * cw[c + 2] + cb[c + 2]);
      pk.h[3] = (__bf16)(v3 * cw[c + 3] + cb[c + 3]);
      const int sl = (((ch4 >> 3) ^ (tokl & 7)) << 3) + (ch4 & 7);
      *(ushort4*)(Al + (tokl << 6) + sl) = pk.u;
    }
    __syncthreads();
    bf16x8 af[4][2];
#pragma unroll
    for (int i = 0; i < 4; ++i) {
      const int ar = wm + i * 16 + lr;
      af[i][0] = *(const bf16x8*)(Al + (ar << 6) + (((lg    ) ^ (ar & 7)) << 3));
      af[i][1] = *(const bf16x8*)(Al + (ar << 6) + (((lg + 4) ^ (ar & 7)) << 3));
    }
#pragma unroll
    for (int j = 0; j < 8; ++j) {
      const int br = wn + j * 16 + lr;
      const bf16x8 b0 = *(const bf16x8*)(Bl + (br << 6) + (((lg    ) ^ (br & 7)) << 3));
      const bf16x8 b1 = *(const bf16x8*)(Bl + (br << 6) + (((lg + 4) ^ (br & 7)) << 3));
#pragma unroll
      for (int i = 0; i < 4; ++i) {
        acc[i][j] = __builtin_amdgcn_mfma_f32_16x16x32_bf16(af[i][0], b0, acc[i][j], 0, 0, 0);
        acc[i][j] = __builtin_amdgcn_mfma_f32_16x16x32_bf16(af[i][1], b1, acc[i][j], 0, 0, 0);
      }
    }
    __syncthreads();
  }

  // epilogue: per-head (64-col group = 4 j-frags) L2 normalization, bf16 out
#pragma unroll
  for (int i = 0; i < 4; ++i) {
#pragma unroll
    for (int r = 0; r < 4; ++r) {
      const int row = m0 + wm + i * 16 + lg4 + r;
#pragma unroll
      for (int h2 = 0; h2 < 2; ++h2) {
        float ss = 0.f;
#pragma unroll
        for (int j = h2 * 4; j < h2 * 4 + 4; ++j) {
          const float v = acc[i][j][r]; ss += v * v;
        }
        ss += __shfl_xor(ss, 1, 64); ss += __shfl_xor(ss, 2, 64);
        ss += __shfl_xor(ss, 4, 64); ss += __shfl_xor(ss, 8, 64);
        const float sc = 1.f / (sqrtf(ss) + 1e-6f);
#pragma unroll
        for (int j = h2 * 4; j < h2 * 4 + 4; ++j)
          qb[(size_t)row * 512 + n0 + wn + j * 16 + lr] = f2b(acc[i][j][r] * sc);
      }
    }
  }
}

// O-proj GEMM (proven R9 structure, unchanged).
__global__ __launch_bounds__(256) void k_gemm2(
    const u16* __restrict__ A, const u16* __restrict__ BT,
    int M, int N, int K,
    float* __restrict__ outf,
    const float* __restrict__ xres, const float* __restrict__ bias) {
  __shared__ u16 Al[128 * 64];
  __shared__ u16 Bl[128 * 64];
  const int tid = threadIdx.x;
  const int l = tid & 63, w = tid >> 6;

  const int nwg = gridDim.x * gridDim.y;
  int lin = blockIdx.y * gridDim.x + blockIdx.x;
  lin = (lin & 7) * (nwg >> 3) + (lin >> 3);
  const int m0 = (lin / gridDim.x) << 7, n0 = (lin % gridDim.x) << 7;

  const int wm = (w >> 1) << 6, wn = (w & 1) << 6;
  const int lr = l & 15, lg = l >> 4;

  f32x4 acc[4][4];
#pragma unroll
  for (int i = 0; i < 4; ++i)
#pragma unroll
    for (int j = 0; j < 4; ++j) acc[i][j] = {0.f, 0.f, 0.f, 0.f};

  const int rl = l >> 3, slot = l & 7;
  const int c8 = (slot ^ rl) << 3;
  int arow[4], brow[4];
#pragma unroll
  for (int j = 0; j < 4; ++j) {
    const int r_local = (w << 5) + (j << 3) + rl;
    arow[j] = min(m0 + r_local, M - 1);
    brow[j] = n0 + r_local;
  }

  const int ksteps = K >> 6;
  for (int ks = 0; ks < ksteps; ++ks) {
    const int kb = (ks << 6) + c8;
#pragma unroll
    for (int j = 0; j < 4; ++j)
      g2lds16(A + (size_t)arow[j] * K + kb, Al + (((w << 5) + (j << 3)) << 6));
#pragma unroll
    for (int j = 0; j < 4; ++j)
      g2lds16(BT + (size_t)brow[j] * K + kb, Bl + (((w << 5) + (j << 3)) << 6));
    __syncthreads();
    bf16x8 bfr[4][2];
#pragma unroll
    for (int j = 0; j < 4; ++j) {
      const int br = wn + j * 16 + lr;
      bfr[j][0] = *(const bf16x8*)(Bl + (br << 6) + (((lg    ) ^ (br & 7)) << 3));
      bfr[j][1] = *(const bf16x8*)(Bl + (br << 6) + (((lg + 4) ^ (br & 7)) << 3));
    }
#pragma unroll
    for (int i = 0; i < 4; ++i) {
      const int ar = wm + i * 16 + lr;
      const bf16x8 a0 = *(const bf16x8*)(Al + (ar << 6) + (((lg    ) ^ (ar & 7)) << 3));
      const bf16x8 a1 = *(const bf16x8*)(Al + (ar << 6) + (((lg + 4) ^ (ar & 7)) << 3));
#pragma unroll
      for (int j = 0; j < 4; ++j) {
        acc[i][j] = __builtin_amdgcn_mfma_f32_16x16x32_bf16(a0, bfr[j][0], acc[i][j], 0, 0, 0);
        acc[i][j] = __builtin_amdgcn_mfma_f32_16x16x32_bf16(a1, bfr[j][1], acc[i][j], 0, 0, 0);
      }
    }
    __syncthreads();
  }

  const int lg4 = lg << 2;
#pragma unroll
  for (int i = 0; i < 4; ++i) {
#pragma unroll
    for (int j = 0; j < 4; ++j) {
#pragma unroll
      for (int r = 0; r < 4; ++r) {
        const int row = m0 + wm + i * 16 + lg4 + r;
        const int col = n0 + wn + j * 16 + lr;
        const int bb = col >> 12, hw = col & 4095;
        const size_t oo = (((size_t)bb << 9) + row) * 4096 + hw;
        outf[oo] = xres[oo] + bias[row] + acc[i][j][r];
      }
    }
  }
}

// MFMA attention. 256 q-rows per block as four 64-row halves over a single
// K/V staging (grid 2048; stage+transpose amortized 256x) — R17 optimum.
__global__ __launch_bounds__(256) void k_attn2(
    const u16* __restrict__ q, const u16* __restrict__ kn,
    const u16* __restrict__ vn, u16* __restrict__ out) {
  __shared__ u16 Kl[96 * 72];
  __shared__ u16 Vt[64 * 104];
  __shared__ u16 Pl[64 * 104];
  const int qt = blockIdx.x, h = blockIdx.y, b = blockIdx.z;
  const size_t kvb = ((size_t)(b * 8 + h)) * (77 * 64);
  const int tid = threadIdx.x;
  for (int u = tid; u < 768; u += 256) {
    const int row = u >> 3, c8v = (u & 7) << 3;
    uint4 v = make_uint4(0, 0, 0, 0);
    if (row < 77) v = *(const uint4*)(kn + kvb + row * 64 + c8v);
    *(uint4*)(Kl + row * 72 + c8v) = v;
  }
  for (int u = tid; u < 768; u += 256) {
    const int row = u >> 3, c8v = (u & 7) << 3;
    uint4 v = make_uint4(0, 0, 0, 0);
    if (row < 77) v = *(const uint4*)(vn + kvb + row * 64 + c8v);
    const u16* pv = (const u16*)&v;
#pragma unroll
    for (int j = 0; j < 8; ++j) Vt[(c8v + j) * 104 + row] = pv[j];
  }
  __syncthreads();
  const int l = tid & 63, w = tid >> 6;
  const int lr = l & 15, lg = l >> 4;

  for (int half = 0; half < 4; ++half) {
    const int qrow = (b << 12) + (qt << 8) + (half << 6) + (w << 4) + lr;
    bf16x8 af0 = *(const bf16x8*)(q + (size_t)qrow * 512 + h * 64 + lg * 8);
    bf16x8 af1 = *(const bf16x8*)(q + (size_t)qrow * 512 + h * 64 + 32 + lg * 8);
    f32x4 s[6];
#pragma unroll
    for (int nt = 0; nt < 6; ++nt) {
      s[nt] = {0.f, 0.f, 0.f, 0.f};
      bf16x8 bk0 = *(const bf16x8*)(Kl + (nt * 16 + lr) * 72 + lg * 8);
      bf16x8 bk1 = *(const bf16x8*)(Kl + (nt * 16 + lr) * 72 + 32 + lg * 8);
      s[nt] = __builtin_amdgcn_mfma_f32_16x16x32_bf16(af0, bk0, s[nt], 0, 0, 0);
      s[nt] = __builtin_amdgcn_mfma_f32_16x16x32_bf16(af1, bk1, s[nt], 0, 0, 0);
    }
#pragma unroll
    for (int r = 0; r < 4; ++r) {
      if (lr >= 13) s[4][r] = -1e30f;
      s[5][r] = -1e30f;
    }
#pragma unroll
    for (int r = 0; r < 4; ++r) {
      float m = s[0][r];
#pragma unroll
      for (int nt = 1; nt < 6; ++nt) m = fmaxf(m, s[nt][r]);
      m = fmaxf(m, __shfl_xor(m, 1, 64)); m = fmaxf(m, __shfl_xor(m, 2, 64));
      m = fmaxf(m, __shfl_xor(m, 4, 64)); m = fmaxf(m, __shfl_xor(m, 8, 64));
      float sum = 0.f;
#pragma unroll
      for (int nt = 0; nt < 6; ++nt) { s[nt][r] = __expf(s[nt][r] - m); sum += s[nt][r]; }
      sum += __shfl_xor(sum, 1, 64); sum += __shfl_xor(sum, 2, 64);
      sum += __shfl_xor(sum, 4, 64); sum += __shfl_xor(sum, 8, 64);
      const float inv = 1.f / sum;
      const int qlocal = (w << 4) + (lg << 2) + r;
#pragma unroll
      for (int nt = 0; nt < 6; ++nt)
        Pl[qlocal * 104 + nt * 16 + lr] = f2b(s[nt][r] * inv);
    }
    __syncthreads();

    bf16x8 pa0 = *(const bf16x8*)(Pl + ((w << 4) + lr) * 104 + lg * 8);
    bf16x8 pa1 = *(const bf16x8*)(Pl + ((w << 4) + lr) * 104 + 32 + lg * 8);
    bf16x8 pa2 = *(const bf16x8*)(Pl + ((w << 4) + lr) * 104 + 64 + lg * 8);
    f32x4 o[4];
#pragma unroll
    for (int nt = 0; nt < 4; ++nt) {
      o[nt] = {0.f, 0.f, 0.f, 0.f};
      bf16x8 bv0 = *(const bf16x8*)(Vt + (nt * 16 + lr) * 104 + lg * 8);
      bf16x8 bv1 = *(const bf16x8*)(Vt + (nt * 16 + lr) * 104 + 32 + lg * 8);
      bf16x8 bv2 = *(const bf16x8*)(Vt + (nt * 16 + lr) * 104 + 64 + lg * 8);
      o[nt] = __builtin_amdgcn_mfma_f32_16x16x32_bf16(pa0, bv0, o[nt], 0, 0, 0);
      o[nt] = __builtin_amdgcn_mfma_f32_16x16x32_bf16(pa1, bv1, o[nt], 0, 0, 0);
      o[nt] = __builtin_amdgcn_mfma_f32_16x16x32_bf16(pa2, bv2, o[nt], 0, 0, 0);
    }
#pragma unroll
    for (int r = 0; r < 4; ++r) {
      const int n = (b << 12) + (qt << 8) + (half << 6) + (w << 4) + (lg << 2) + r;
#pragma unroll
      for (int nt = 0; nt < 4; ++nt)
        out[(size_t)n * 512 + h * 64 + nt * 16 + lr] = f2b(o[nt][r]);
    }
    __syncthreads();   // all waves done reading Pl before next half rewrites
  }
}

extern "C" void kernel_launch(void* const* d_in, const int* in_sizes, int n_in,
                              void* d_out, int out_size, void* d_ws, size_t ws_size,
                              hipStream_t stream) {
  (void)in_sizes; (void)n_in; (void)out_size; (void)ws_size;
  const float* x    = (const float*)d_in[0];
  const float* text = (const float*)d_in[1];
  const float* gnw  = (const float*)d_in[2];
  const float* gnb  = (const float*)d_in[3];
  const float* Wq   = (const float*)d_in[4];
  const float* Wk   = (const float*)d_in[5];
  const float* Wv   = (const float*)d_in[6];
  const float* Wo   = (const float*)d_in[7];
  const float* bo   = (const float*)d_in[8];
  float* out = (float*)d_out;

  char* ws = (char*)d_ws;
  size_t off = 0;
  auto alloc = [&](size_t bytes) -> void* {
    void* p = ws + off; off += (bytes + 255) & ~(size_t)255; return p;
  };
  float* stats = (float*)alloc(512 * 2 * 4);
  u16* wq_b    = (u16*)alloc((size_t)512 * 512 * 2);
  u16* wkv_b   = (u16*)alloc((size_t)1024 * 768 * 2);
  u16* wo_b    = (u16*)alloc((size_t)512 * 512 * 2);
  u16* text_b  = (u16*)alloc((size_t)1232 * 768 * 2);
  u16* kn      = (u16*)alloc((size_t)16 * 8 * 77 * 64 * 2);
  u16* vn      = (u16*)alloc((size_t)16 * 8 * 77 * 64 * 2);
  u16* ao      = (u16*)alloc((size_t)65536 * 512 * 2);  // attention output
  u16* qb      = (u16*)alloc((size_t)65536 * 512 * 2);

  // blocks 0..511: GN stats; blocks 512..1023: weight/text bf16 casts
  k_prep<<<dim3(1024), 256, 0, stream>>>(x, stats, Wq, Wk, Wv, Wo, text,
                                         wq_b, wkv_b, wo_b, text_b);

  // blocks 0..1023: q = gn(x)^T @ Wq^T (fused GN + q-norm)
  // blocks 1024..1103: kn/vn = text @ Wkv^T with fused per-head k-norm
  k_qproj_kv<<<dim3(1104), 256, 0, stream>>>(x, stats, gnw, gnb, wq_b, qb,
                                             text_b, wkv_b, kn, vn);

  k_attn2<<<dim3(16, 8, 16), 256, 0, stream>>>(qb, kn, vn, ao);

  // out^T = Wo @ attn^T with fused bias + residual, written as [B,C,HW]
  k_gemm2<<<dim3(512, 4), 256, 0, stream>>>(wo_b, ao, 512, 65536, 512,
                                            out, x, bo);
}

// Round 20
// 267.347 us; speedup vs baseline: 1.0046x; 1.0035x over previous
//
#include <hip/hip_runtime.h>
#include <math.h>

// CrossAttentionBlock: GN(32) -> q = xn@Wq^T ; k,v = text@W{k,v}^T ; cosine-sim
// attention (nh=8, hd=64, N_text=77) -> out@Wo^T + bo -> residual add.
// B=16, C=512, HW=4096, TD=768.  bf16 MFMA (16x16x32), fp32 accum.
// TERMINAL CONFIG (R17, reproduced 267.9/268.6/268.3 us):
//   k_prep      : gnstats + weight/text casts packed into one 1024-blk launch
//   k_qproj_kv  : GN+Qproj+q-norm (1024 blks) || KV GEMM+k-norm (80 blks)
//   k_attn2     : MFMA attention, 256 q-rows/blk, 4 halves per K/V staging
//   k_gemm2     : O-proj 128x128/BK64 XOR-swizzled + fused bias/residual
// Falsified structural levers (counter-diagnosed): R4 dbuf, R6 counted-vmcnt,
// R7 retile, R8 vertical fusion, R10 LDS-repack, R11 L2-direct B, R12 NT ops,
// R18 512-row attn. Remaining gap (~50us/GEMM) requires the 256^2 8-wave
// 8-phase schedule (m248), unverifiable one-shot at this geometry (m232/m152).

typedef unsigned short u16;
typedef __attribute__((ext_vector_type(8))) __bf16 bf16x8;
typedef __attribute__((ext_vector_type(4))) float f32x4;

typedef __attribute__((address_space(1))) unsigned int as1_u32;
typedef __attribute__((address_space(3))) unsigned int as3_u32;

__device__ __forceinline__ float b2f(u16 u) {
  union { unsigned int i; float f; } c; c.i = ((unsigned int)u) << 16; return c.f;
}
__device__ __forceinline__ u16 f2b(float f) {
  union { float f; unsigned int i; } c; c.f = f;
  unsigned int i = c.i + 0x7fffu + ((c.i >> 16) & 1u);  // RNE
  return (u16)(i >> 16);
}

// 16B-per-lane async global->LDS. LDS dest is wave-uniform base; HW adds lane*16.
__device__ __forceinline__ void g2lds16(const void* g, void* l) {
  __builtin_amdgcn_global_load_lds((const as1_u32*)g, (as3_u32*)l, 16, 0, 0);
}

// Merged prep: blocks 0..511 = GN stats (one block per (b,group));
// blocks 512..1023 = weight/text bf16 casts (grid-stride over 512 blocks).
__global__ __launch_bounds__(256) void k_prep(
    const float* __restrict__ x, float* __restrict__ stats,
    const float* __restrict__ Wq, const float* __restrict__ Wk,
    const float* __restrict__ Wv, const float* __restrict__ Wo,
    const float* __restrict__ text,
    u16* __restrict__ wq_b, u16* __restrict__ wkv_b,
    u16* __restrict__ wo_b, u16* __restrict__ text_b) {
  if (blockIdx.x >= 512) {
    const int i = (blockIdx.x - 512) * 256 + threadIdx.x;
    const int st = 512 * 256;
    for (int j = i; j < 262144; j += st) wq_b[j] = f2b(Wq[j]);
    for (int j = i; j < 393216; j += st) wkv_b[j] = f2b(Wk[j]);
    for (int j = i; j < 393216; j += st) wkv_b[393216 + j] = f2b(Wv[j]);
    for (int j = i; j < 262144; j += st) wo_b[j] = f2b(Wo[j]);
    for (int j = i; j < 946176; j += st) text_b[j] = f2b(text[j]);
    return;
  }
  const int bg = blockIdx.x;
  const float4* p = (const float4*)(x + (size_t)bg * 65536);
  float s = 0.f, ss = 0.f;
  for (int i = threadIdx.x; i < 16384; i += 256) {
    float4 v = p[i];
    s  += v.x + v.y + v.z + v.w;
    ss += v.x*v.x + v.y*v.y + v.z*v.z + v.w*v.w;
  }
  for (int o = 1; o < 64; o <<= 1) { s += __shfl_xor(s, o, 64); ss += __shfl_xor(ss, o, 64); }
  __shared__ float as_[4], bs_[4];
  int w = threadIdx.x >> 6;
  if ((threadIdx.x & 63) == 0) { as_[w] = s; bs_[w] = ss; }
  __syncthreads();
  if (threadIdx.x == 0) {
    s  = as_[0] + as_[1] + as_[2] + as_[3];
    ss = bs_[0] + bs_[1] + bs_[2] + bs_[3];
    float mu  = s * (1.f / 65536.f);
    float var = ss * (1.f / 65536.f) - mu * mu;
    stats[2*bg]   = mu;
    stats[2*bg+1] = rsqrtf(var + 1e-5f);
  }
}

// Combined launch:
//  blocks 0..1023   : fused GN + Q-projection + per-head q L2-norm (R9 path).
//  blocks 1024..1103: KV GEMM with fused per-head k L2-norm epilogue.
__global__ __launch_bounds__(256, 2) void k_qproj_kv(
    const float* __restrict__ x, const float* __restrict__ stats,
    const float* __restrict__ gw, const float* __restrict__ gb,
    const u16* __restrict__ Wqb, u16* __restrict__ qb,
    const u16* __restrict__ textb, const u16* __restrict__ wkvb,
    u16* __restrict__ kn, u16* __restrict__ vn) {
  __shared__ u16 Al[128 * 64];
  __shared__ u16 Bl[256 * 64];
  __shared__ float cw[512], cb[512];
  const int tid = threadIdx.x;
  const int l = tid & 63, w = tid >> 6;
  const int lr = l & 15, lg = l >> 4;
  const int lg4 = lg << 2;
  const int rl = l >> 3, slot = l & 7;
  const int c8 = (slot ^ rl) << 3;

  if (blockIdx.x >= 1024) {
    // ---------------- KV GEMM path ----------------
    const int kb = blockIdx.x - 1024;
    const int m0 = (kb >> 3) << 7, n0 = (kb & 7) << 7;
    const int wm = (w >> 1) << 6, wn = (w & 1) << 6;

    f32x4 acc[4][4];
#pragma unroll
    for (int i = 0; i < 4; ++i)
#pragma unroll
      for (int j = 0; j < 4; ++j) acc[i][j] = {0.f, 0.f, 0.f, 0.f};

    int arow[4], brow[4];
#pragma unroll
    for (int j = 0; j < 4; ++j) {
      const int r_local = (w << 5) + (j << 3) + rl;
      arow[j] = min(m0 + r_local, 1231);
      brow[j] = n0 + r_local;
    }

    for (int ks = 0; ks < 12; ++ks) {
      const int kcol = (ks << 6) + c8;
#pragma unroll
      for (int j = 0; j < 4; ++j)
        g2lds16(textb + (size_t)arow[j] * 768 + kcol, Al + (((w << 5) + (j << 3)) << 6));
#pragma unroll
      for (int j = 0; j < 4; ++j)
        g2lds16(wkvb + (size_t)brow[j] * 768 + kcol, Bl + (((w << 5) + (j << 3)) << 6));
      __syncthreads();
      bf16x8 bfr[4][2];
#pragma unroll
      for (int j = 0; j < 4; ++j) {
        const int br = wn + j * 16 + lr;
        bfr[j][0] = *(const bf16x8*)(Bl + (br << 6) + (((lg    ) ^ (br & 7)) << 3));
        bfr[j][1] = *(const bf16x8*)(Bl + (br << 6) + (((lg + 4) ^ (br & 7)) << 3));
      }
#pragma unroll
      for (int i = 0; i < 4; ++i) {
        const int ar = wm + i * 16 + lr;
        const bf16x8 a0 = *(const bf16x8*)(Al + (ar << 6) + (((lg    ) ^ (ar & 7)) << 3));
        const bf16x8 a1 = *(const bf16x8*)(Al + (ar << 6) + (((lg + 4) ^ (ar & 7)) << 3));
#pragma unroll
        for (int j = 0; j < 4; ++j) {
          acc[i][j] = __builtin_amdgcn_mfma_f32_16x16x32_bf16(a0, bfr[j][0], acc[i][j], 0, 0, 0);
          acc[i][j] = __builtin_amdgcn_mfma_f32_16x16x32_bf16(a1, bfr[j][1], acc[i][j], 0, 0, 0);
        }
      }
      __syncthreads();
    }

    // fused epilogue: cols 0-511 = k (per-head L2 norm), 512-1023 = v (cast).
    const int col0 = n0 + wn;
#pragma unroll
    for (int i = 0; i < 4; ++i) {
#pragma unroll
      for (int r = 0; r < 4; ++r) {
        const int row = m0 + wm + i * 16 + lg4 + r;
        if (row < 1232) {
          const int bq = row / 77, tq = row - bq * 77;
          if (col0 < 512) {
            float ss = 0.f;
#pragma unroll
            for (int j = 0; j < 4; ++j) { const float v = acc[i][j][r]; ss += v * v; }
            ss += __shfl_xor(ss, 1, 64); ss += __shfl_xor(ss, 2, 64);
            ss += __shfl_xor(ss, 4, 64); ss += __shfl_xor(ss, 8, 64);
            const float sc = 1.f / (sqrtf(ss) + 1e-6f);
            const int h = col0 >> 6;
            const size_t ob = (((size_t)(bq * 8 + h)) * 77 + tq) * 64;
#pragma unroll
            for (int j = 0; j < 4; ++j)
              kn[ob + j * 16 + lr] = f2b(acc[i][j][r] * sc);
          } else {
            const int h = (col0 - 512) >> 6;
            const size_t ob = (((size_t)(bq * 8 + h)) * 77 + tq) * 64;
#pragma unroll
            for (int j = 0; j < 4; ++j)
              vn[ob + j * 16 + lr] = f2b(acc[i][j][r]);
          }
        }
      }
    }
    return;
  }

  // ---------------- qproj path (R9, unchanged) ----------------
  const int o = blockIdx.x;
  const int mi = ((o >> 4) << 3) + (o & 7);   // 0..511 token tile
  const int ni = (o >> 3) & 1;                // 0..1   out-channel half
  const int m0 = mi << 7, n0 = ni << 8;
  const int b = m0 >> 12, hw0 = m0 & 4095;

  for (int c = tid; c < 512; c += 256) {
    const int g = (b << 5) + (c >> 4);
    const float mu = stats[2*g], rs = stats[2*g+1];
    const float wg = gw[c] * rs;
    cw[c] = wg; cb[c] = gb[c] - mu * wg;
  }

  const int wm = (w & 1) << 6;          // token base within tile
  const int wn = (w >> 1) << 7;         // out-ch base within tile

  f32x4 acc[4][8];
#pragma unroll
  for (int i = 0; i < 4; ++i)
#pragma unroll
    for (int j = 0; j < 8; ++j) acc[i][j] = {0.f, 0.f, 0.f, 0.f};

  int brow[8];
#pragma unroll
  for (int j = 0; j < 8; ++j) brow[j] = n0 + (w << 6) + (j << 3) + rl;

  const int tokl = tid & 127;
  const int chg = tid >> 7;
  const float* xb = x + (((size_t)b) << 9) * 4096;
  __syncthreads();  // cw/cb ready

  for (int ks = 0; ks < 8; ++ks) {
#pragma unroll
    for (int j = 0; j < 8; ++j)
      g2lds16(Wqb + (size_t)brow[j] * 512 + (ks << 6) + c8,
              Bl + (((w << 6) + (j << 3)) << 6));
    // A tile: 8 iters x 4 channels, 1 token per thread
#pragma unroll
    for (int jj = 0; jj < 8; ++jj) {
      const int ch4 = (((chg << 3) + jj) << 2);   // 0..60 step 4
      const int c = (ks << 6) + ch4;
      const float v0 = xb[(size_t)(c + 0) * 4096 + hw0 + tokl];
      const float v1 = xb[(size_t)(c + 1) * 4096 + hw0 + tokl];
      const float v2 = xb[(size_t)(c + 2) * 4096 + hw0 + tokl];
      const float v3 = xb[(size_t)(c + 3) * 4096 + hw0 + tokl];
      union { __bf16 h[4]; ushort4 u; } pk;
      pk.h[0] = (__bf16)(v0 * cw[c + 0] + cb[c + 0]);
      pk.h[1] = (__bf16)(v1 * cw[c + 1] + cb[c + 1]);
      pk.h[2] = (__bf16)(v2 * cw[c + 2] + cb[c + 2]);
      pk.h[3] = (__bf16)(v3 * cw[c + 3] + cb[c + 3]);
      const int sl = (((ch4 >> 3) ^ (tokl & 7)) << 3) + (ch4 & 7);
      *(ushort4*)(Al + (tokl << 6) + sl) = pk.u;
    }
    __syncthreads();
    bf16x8 af[4][2];
#pragma unroll
    for (int i = 0; i < 4; ++i) {
      const int ar = wm + i * 16 + lr;
      af[i][0] = *(const bf16x8*)(Al + (ar << 6) + (((lg    ) ^ (ar & 7)) << 3));
      af[i][1] = *(const bf16x8*)(Al + (ar << 6) + (((lg + 4) ^ (ar & 7)) << 3));
    }
#pragma unroll
    for (int j = 0; j < 8; ++j) {
      const int br = wn + j * 16 + lr;
      const bf16x8 b0 = *(const bf16x8*)(Bl + (br << 6) + (((lg    ) ^ (br & 7)) << 3));
      const bf16x8 b1 = *(const bf16x8*)(Bl + (br << 6) + (((lg + 4) ^ (br & 7)) << 3));
#pragma unroll
      for (int i = 0; i < 4; ++i) {
        acc[i][j] = __builtin_amdgcn_mfma_f32_16x16x32_bf16(af[i][0], b0, acc[i][j], 0, 0, 0);
        acc[i][j] = __builtin_amdgcn_mfma_f32_16x16x32_bf16(af[i][1], b1, acc[i][j], 0, 0, 0);
      }
    }
    __syncthreads();
  }

  // epilogue: per-head (64-col group = 4 j-frags) L2 normalization, bf16 out
#pragma unroll
  for (int i = 0; i < 4; ++i) {
#pragma unroll
    for (int r = 0; r < 4; ++r) {
      const int row = m0 + wm + i * 16 + lg4 + r;
#pragma unroll
      for (int h2 = 0; h2 < 2; ++h2) {
        float ss = 0.f;
#pragma unroll
        for (int j = h2 * 4; j < h2 * 4 + 4; ++j) {
          const float v = acc[i][j][r]; ss += v * v;
        }
        ss += __shfl_xor(ss, 1, 64); ss += __shfl_xor(ss, 2, 64);
        ss += __shfl_xor(ss, 4, 64); ss += __shfl_xor(ss, 8, 64);
        const float sc = 1.f / (sqrtf(ss) + 1e-6f);
#pragma unroll
        for (int j = h2 * 4; j < h2 * 4 + 4; ++j)
          qb[(size_t)row * 512 + n0 + wn + j * 16 + lr] = f2b(acc[i][j][r] * sc);
      }
    }
  }
}

// O-proj GEMM (proven R9 structure, unchanged).
__global__ __launch_bounds__(256) void k_gemm2(
    const u16* __restrict__ A, const u16* __restrict__ BT,
    int M, int N, int K,
    float* __restrict__ outf,
    const float* __restrict__ xres, const float* __restrict__ bias) {
  __shared__ u16 Al[128 * 64];
  __shared__ u16 Bl[128 * 64];
  const int tid = threadIdx.x;
  const int l = tid & 63, w = tid >> 6;

  const int nwg = gridDim.x * gridDim.y;
  int lin = blockIdx.y * gridDim.x + blockIdx.x;
  lin = (lin & 7) * (nwg >> 3) + (lin >> 3);
  const int m0 = (lin / gridDim.x) << 7, n0 = (lin % gridDim.x) << 7;

  const int wm = (w >> 1) << 6, wn = (w & 1) << 6;
  const int lr = l & 15, lg = l >> 4;

  f32x4 acc[4][4];
#pragma unroll
  for (int i = 0; i < 4; ++i)
#pragma unroll
    for (int j = 0; j < 4; ++j) acc[i][j] = {0.f, 0.f, 0.f, 0.f};

  const int rl = l >> 3, slot = l & 7;
  const int c8 = (slot ^ rl) << 3;
  int arow[4], brow[4];
#pragma unroll
  for (int j = 0; j < 4; ++j) {
    const int r_local = (w << 5) + (j << 3) + rl;
    arow[j] = min(m0 + r_local, M - 1);
    brow[j] = n0 + r_local;
  }

  const int ksteps = K >> 6;
  for (int ks = 0; ks < ksteps; ++ks) {
    const int kb = (ks << 6) + c8;
#pragma unroll
    for (int j = 0; j < 4; ++j)
      g2lds16(A + (size_t)arow[j] * K + kb, Al + (((w << 5) + (j << 3)) << 6));
#pragma unroll
    for (int j = 0; j < 4; ++j)
      g2lds16(BT + (size_t)brow[j] * K + kb, Bl + (((w << 5) + (j << 3)) << 6));
    __syncthreads();
    bf16x8 bfr[4][2];
#pragma unroll
    for (int j = 0; j < 4; ++j) {
      const int br = wn + j * 16 + lr;
      bfr[j][0] = *(const bf16x8*)(Bl + (br << 6) + (((lg    ) ^ (br & 7)) << 3));
      bfr[j][1] = *(const bf16x8*)(Bl + (br << 6) + (((lg + 4) ^ (br & 7)) << 3));
    }
#pragma unroll
    for (int i = 0; i < 4; ++i) {
      const int ar = wm + i * 16 + lr;
      const bf16x8 a0 = *(const bf16x8*)(Al + (ar << 6) + (((lg    ) ^ (ar & 7)) << 3));
      const bf16x8 a1 = *(const bf16x8*)(Al + (ar << 6) + (((lg + 4) ^ (ar & 7)) << 3));
#pragma unroll
      for (int j = 0; j < 4; ++j) {
        acc[i][j] = __builtin_amdgcn_mfma_f32_16x16x32_bf16(a0, bfr[j][0], acc[i][j], 0, 0, 0);
        acc[i][j] = __builtin_amdgcn_mfma_f32_16x16x32_bf16(a1, bfr[j][1], acc[i][j], 0, 0, 0);
      }
    }
    __syncthreads();
  }

  const int lg4 = lg << 2;
#pragma unroll
  for (int i = 0; i < 4; ++i) {
#pragma unroll
    for (int j = 0; j < 4; ++j) {
#pragma unroll
      for (int r = 0; r < 4; ++r) {
        const int row = m0 + wm + i * 16 + lg4 + r;
        const int col = n0 + wn + j * 16 + lr;
        const int bb = col >> 12, hw = col & 4095;
        const size_t oo = (((size_t)bb << 9) + row) * 4096 + hw;
        outf[oo] = xres[oo] + bias[row] + acc[i][j][r];
      }
    }
  }
}

// MFMA attention. 256 q-rows per block as four 64-row halves over a single
// K/V staging (grid 2048; stage+transpose amortized 256x) — R17 optimum.
__global__ __launch_bounds__(256) void k_attn2(
    const u16* __restrict__ q, const u16* __restrict__ kn,
    const u16* __restrict__ vn, u16* __restrict__ out) {
  __shared__ u16 Kl[96 * 72];
  __shared__ u16 Vt[64 * 104];
  __shared__ u16 Pl[64 * 104];
  const int qt = blockIdx.x, h = blockIdx.y, b = blockIdx.z;
  const size_t kvb = ((size_t)(b * 8 + h)) * (77 * 64);
  const int tid = threadIdx.x;
  for (int u = tid; u < 768; u += 256) {
    const int row = u >> 3, c8v = (u & 7) << 3;
    uint4 v = make_uint4(0, 0, 0, 0);
    if (row < 77) v = *(const uint4*)(kn + kvb + row * 64 + c8v);
    *(uint4*)(Kl + row * 72 + c8v) = v;
  }
  for (int u = tid; u < 768; u += 256) {
    const int row = u >> 3, c8v = (u & 7) << 3;
    uint4 v = make_uint4(0, 0, 0, 0);
    if (row < 77) v = *(const uint4*)(vn + kvb + row * 64 + c8v);
    const u16* pv = (const u16*)&v;
#pragma unroll
    for (int j = 0; j < 8; ++j) Vt[(c8v + j) * 104 + row] = pv[j];
  }
  __syncthreads();
  const int l = tid & 63, w = tid >> 6;
  const int lr = l & 15, lg = l >> 4;

  for (int half = 0; half < 4; ++half) {
    const int qrow = (b << 12) + (qt << 8) + (half << 6) + (w << 4) + lr;
    bf16x8 af0 = *(const bf16x8*)(q + (size_t)qrow * 512 + h * 64 + lg * 8);
    bf16x8 af1 = *(const bf16x8*)(q + (size_t)qrow * 512 + h * 64 + 32 + lg * 8);
    f32x4 s[6];
#pragma unroll
    for (int nt = 0; nt < 6; ++nt) {
      s[nt] = {0.f, 0.f, 0.f, 0.f};
      bf16x8 bk0 = *(const bf16x8*)(Kl + (nt * 16 + lr) * 72 + lg * 8);
      bf16x8 bk1 = *(const bf16x8*)(Kl + (nt * 16 + lr) * 72 + 32 + lg * 8);
      s[nt] = __builtin_amdgcn_mfma_f32_16x16x32_bf16(af0, bk0, s[nt], 0, 0, 0);
      s[nt] = __builtin_amdgcn_mfma_f32_16x16x32_bf16(af1, bk1, s[nt], 0, 0, 0);
    }
#pragma unroll
    for (int r = 0; r < 4; ++r) {
      if (lr >= 13) s[4][r] = -1e30f;
      s[5][r] = -1e30f;
    }
#pragma unroll
    for (int r = 0; r < 4; ++r) {
      float m = s[0][r];
#pragma unroll
      for (int nt = 1; nt < 6; ++nt) m = fmaxf(m, s[nt][r]);
      m = fmaxf(m, __shfl_xor(m, 1, 64)); m = fmaxf(m, __shfl_xor(m, 2, 64));
      m = fmaxf(m, __shfl_xor(m, 4, 64)); m = fmaxf(m, __shfl_xor(m, 8, 64));
      float sum = 0.f;
#pragma unroll
      for (int nt = 0; nt < 6; ++nt) { s[nt][r] = __expf(s[nt][r] - m); sum += s[nt][r]; }
      sum += __shfl_xor(sum, 1, 64); sum += __shfl_xor(sum, 2, 64);
      sum += __shfl_xor(sum, 4, 64); sum += __shfl_xor(sum, 8, 64);
      const float inv = 1.f / sum;
      const int qlocal = (w << 4) + (lg << 2) + r;
#pragma unroll
      for (int nt = 0; nt < 6; ++nt)
        Pl[qlocal * 104 + nt * 16 + lr] = f2b(s[nt][r] * inv);
    }
    __syncthreads();

    bf16x8 pa0 = *(const bf16x8*)(Pl + ((w << 4) + lr) * 104 + lg * 8);
    bf16x8 pa1 = *(const bf16x8*)(Pl + ((w << 4) + lr) * 104 + 32 + lg * 8);
    bf16x8 pa2 = *(const bf16x8*)(Pl + ((w << 4) + lr) * 104 + 64 + lg * 8);
    f32x4 o[4];
#pragma unroll
    for (int nt = 0; nt < 4; ++nt) {
      o[nt] = {0.f, 0.f, 0.f, 0.f};
      bf16x8 bv0 = *(const bf16x8*)(Vt + (nt * 16 + lr) * 104 + lg * 8);
      bf16x8 bv1 = *(const bf16x8*)(Vt + (nt * 16 + lr) * 104 + 32 + lg * 8);
      bf16x8 bv2 = *(const bf16x8*)(Vt + (nt * 16 + lr) * 104 + 64 + lg * 8);
      o[nt] = __builtin_amdgcn_mfma_f32_16x16x32_bf16(pa0, bv0, o[nt], 0, 0, 0);
      o[nt] = __builtin_amdgcn_mfma_f32_16x16x32_bf16(pa1, bv1, o[nt], 0, 0, 0);
      o[nt] = __builtin_amdgcn_mfma_f32_16x16x32_bf16(pa2, bv2, o[nt], 0, 0, 0);
    }
#pragma unroll
    for (int r = 0; r < 4; ++r) {
      const int n = (b << 12) + (qt << 8) + (half << 6) + (w << 4) + (lg << 2) + r;
#pragma unroll
      for (int nt = 0; nt < 4; ++nt)
        out[(size_t)n * 512 + h * 64 + nt * 16 + lr] = f2b(o[nt][r]);
    }
    __syncthreads();   // all waves done reading Pl before next half rewrites
  }
}

extern "C" void kernel_launch(void* const* d_in, const int* in_sizes, int n_in,
                              void* d_out, int out_size, void* d_ws, size_t ws_size,
                              hipStream_t stream) {
  (void)in_sizes; (void)n_in; (void)out_size; (void)ws_size;
  const float* x    = (const float*)d_in[0];
  const float* text = (const float*)d_in[1];
  const float* gnw  = (const float*)d_in[2];
  const float* gnb  = (const float*)d_in[3];
  const float* Wq   = (const float*)d_in[4];
  const float* Wk   = (const float*)d_in[5];
  const float* Wv   = (const float*)d_in[6];
  const float* Wo   = (const float*)d_in[7];
  const float* bo   = (const float*)d_in[8];
  float* out = (float*)d_out;

  char* ws = (char*)d_ws;
  size_t off = 0;
  auto alloc = [&](size_t bytes) -> void* {
    void* p = ws + off; off += (bytes + 255) & ~(size_t)255; return p;
  };
  float* stats = (float*)alloc(512 * 2 * 4);
  u16* wq_b    = (u16*)alloc((size_t)512 * 512 * 2);
  u16* wkv_b   = (u16*)alloc((size_t)1024 * 768 * 2);
  u16* wo_b    = (u16*)alloc((size_t)512 * 512 * 2);
  u16* text_b  = (u16*)alloc((size_t)1232 * 768 * 2);
  u16* kn      = (u16*)alloc((size_t)16 * 8 * 77 * 64 * 2);
  u16* vn      = (u16*)alloc((size_t)16 * 8 * 77 * 64 * 2);
  u16* ao      = (u16*)alloc((size_t)65536 * 512 * 2);  // attention output
  u16* qb      = (u16*)alloc((size_t)65536 * 512 * 2);

  // blocks 0..511: GN stats; blocks 512..1023: weight/text bf16 casts
  k_prep<<<dim3(1024), 256, 0, stream>>>(x, stats, Wq, Wk, Wv, Wo, text,
                                         wq_b, wkv_b, wo_b, text_b);

  // blocks 0..1023: q = gn(x)^T @ Wq^T (fused GN + q-norm)
  // blocks 1024..1103: kn/vn = text @ Wkv^T with fused per-head k-norm
  k_qproj_kv<<<dim3(1104), 256, 0, stream>>>(x, stats, gnw, gnb, wq_b, qb,
                                             text_b, wkv_b, kn, vn);

  k_attn2<<<dim3(16, 8, 16), 256, 0, stream>>>(qb, kn, vn, ao);

  // out^T = Wo @ attn^T with fused bias + residual, written as [B,C,HW]
  k_gemm2<<<dim3(512, 4), 256, 0, stream>>>(wo_b, ao, 512, 65536, 512,
                                            out, x, bo);
}